// Round 7
// baseline (282.628 us; speedup 1.0000x reference)
//
#include <hip/hip_runtime.h>
#include <hip/hip_bf16.h>

#define N_NODES 4096
#define DIMC    256   // H*D, also K of both layer GEMMs
#define NHEADS  4
#define LOG2E   1.44269504f

typedef __attribute__((ext_vector_type(8))) short  short8;
typedef __attribute__((ext_vector_type(4))) short  short4v;
typedef __attribute__((ext_vector_type(4))) float  float4v;

union S8U { short8 v; unsigned int u[4]; };

#if __has_builtin(__builtin_amdgcn_exp2f)
#define EXP2(x) __builtin_amdgcn_exp2f(x)
#else
#define EXP2(x) exp2f(x)
#endif

__device__ inline unsigned short bf16_bits(__hip_bfloat16 b) {
  union { __hip_bfloat16 b; unsigned short u; } cv; cv.b = b; return cv.u;
}

// ---------------- adjacency -> bitmask (1 bit per edge) ----------------
__global__ __launch_bounds__(256) void pack_adj_kernel(
    const int* __restrict__ adj, unsigned long long* __restrict__ bits)
{
  int wid  = blockIdx.x * 4 + (threadIdx.x >> 6);
  int lane = threadIdx.x & 63;
  int row  = wid >> 6;
  int w64  = wid & 63;
  int v = adj[(size_t)row * N_NODES + w64 * 64 + lane];
  unsigned long long m = __ballot(v > 0);
  if (lane == 0) bits[row * 64 + w64] = m;
}

// ------------- fp32 -> split bf16 (hi + residual lo), elementwise --------
__global__ __launch_bounds__(256) void split_kernel(
    const float* __restrict__ in, __hip_bfloat16* __restrict__ hi,
    __hip_bfloat16* __restrict__ lo, int n)
{
  int i = blockIdx.x * 256 + threadIdx.x;
  if (i < n) {
    float v = in[i];
    __hip_bfloat16 h = __float2bfloat16(v);
    hi[i] = h;
    lo[i] = __float2bfloat16(v - __bfloat162float(h));
  }
}

// ------- fp32 transpose + split: in[B][R][C] -> outhi/lo[B][C][R] --------
// grid (R/32, C/32, B), block 256. (used for W only)
__global__ __launch_bounds__(256) void transpose_split_kernel(
    const float* __restrict__ in, __hip_bfloat16* __restrict__ outhi,
    __hip_bfloat16* __restrict__ outlo, int R, int C)
{
  __shared__ float tile[32][33];
  int t = threadIdx.x;
  int r0 = blockIdx.x * 32, c0 = blockIdx.y * 32;
  size_t base = (size_t)blockIdx.z * R * C;
  int tr = t >> 3, tc = (t & 7) * 4;
  const float* ip = in + base;
  float4v v = *reinterpret_cast<const float4v*>(ip + (size_t)(r0 + tr) * C + c0 + tc);
#pragma unroll
  for (int k = 0; k < 4; ++k) tile[tr][tc + k] = v[k];
  __syncthreads();
  short4v oh, ol;
#pragma unroll
  for (int k = 0; k < 4; ++k) {
    float f = tile[tc + k][tr];
    __hip_bfloat16 hb = __float2bfloat16(f);
    __hip_bfloat16 lb = __float2bfloat16(f - __bfloat162float(hb));
    oh[k] = (short)bf16_bits(hb);
    ol[k] = (short)bf16_bits(lb);
  }
  size_t oidx = base + (size_t)(c0 + tr) * R + r0 + tc;
  *reinterpret_cast<short4v*>(reinterpret_cast<unsigned short*>(outhi) + oidx) = oh;
  *reinterpret_cast<short4v*>(reinterpret_cast<unsigned short*>(outlo) + oidx) = ol;
}

// ---------------- h GEMM (split-bf16, 32x32 tiles) -----------------------
// out[n][c] = sum_k X[n][k]*WT[c][k]. grid (128,8), block 256. Epilogue
// writes row-major fp32 hA AND transposed bf16 hT[c][n].
__global__ __launch_bounds__(256) void gemm_kernel(
    const __hip_bfloat16* __restrict__ Xhi, const __hip_bfloat16* __restrict__ Xlo,
    const __hip_bfloat16* __restrict__ WThi, const __hip_bfloat16* __restrict__ WTlo,
    float* __restrict__ out, __hip_bfloat16* __restrict__ outT)
{
  int t = threadIdx.x;
  int wv = t >> 6, lane = t & 63, quad = lane >> 4, col = lane & 15;
  int r0 = blockIdx.x * 32 + (wv >> 1) * 16;
  int c0 = blockIdx.y * 32 + (wv & 1) * 16;
  float4v acc = {0, 0, 0, 0};
  const unsigned short* Xh = reinterpret_cast<const unsigned short*>(Xhi);
  const unsigned short* Xl = reinterpret_cast<const unsigned short*>(Xlo);
  const unsigned short* Wh = reinterpret_cast<const unsigned short*>(WThi);
  const unsigned short* Wl = reinterpret_cast<const unsigned short*>(WTlo);
#pragma unroll
  for (int k0 = 0; k0 < DIMC; k0 += 32) {
    size_t ao = (size_t)(r0 + col) * DIMC + k0 + quad * 8;
    size_t bo = (size_t)(c0 + col) * DIMC + k0 + quad * 8;
    short8 ah = *reinterpret_cast<const short8*>(Xh + ao);
    short8 al = *reinterpret_cast<const short8*>(Xl + ao);
    short8 bh = *reinterpret_cast<const short8*>(Wh + bo);
    short8 bl = *reinterpret_cast<const short8*>(Wl + bo);
    acc = __builtin_amdgcn_mfma_f32_16x16x32_bf16(ah, bh, acc, 0, 0, 0);
    acc = __builtin_amdgcn_mfma_f32_16x16x32_bf16(ah, bl, acc, 0, 0, 0);
    acc = __builtin_amdgcn_mfma_f32_16x16x32_bf16(al, bh, acc, 0, 0, 0);
  }
  int c = c0 + col;
#pragma unroll
  for (int r = 0; r < 4; ++r)
    out[(size_t)(r0 + quad * 4 + r) * DIMC + c] = acc[r];
  short4v tv;
#pragma unroll
  for (int r = 0; r < 4; ++r)
    tv[r] = (short)bf16_bits(__float2bfloat16(acc[r]));
  *reinterpret_cast<short4v*>(
      reinterpret_cast<unsigned short*>(outT) + (size_t)c * N_NODES + r0 + quad * 4) = tv;
}

// ---- f1L (log2, fp32) + bf16 exp tables E2p/E2n from hA; block max ------
// grid 1024, block 256: wave per node. NO global atomics.
__global__ __launch_bounds__(256) void fvec_kernel(
    const float* __restrict__ hA, const float* __restrict__ a,
    float* __restrict__ f1L, __hip_bfloat16* __restrict__ E2p,
    __hip_bfloat16* __restrict__ E2n, float* __restrict__ pmax)
{
  __shared__ float bm[4][4];  // [wave][head]
  int t = threadIdx.x, wv = t >> 6, lane = t & 63;
  int n = blockIdx.x * 4 + wv;
  int h = lane >> 4, d4 = (lane & 15) * 4;
  float4v v = *reinterpret_cast<const float4v*>(hA + (size_t)n * DIMC + lane * 4);
  const float* ah = a + h * 128;
  float s1 = v[0]*ah[d4] + v[1]*ah[d4+1] + v[2]*ah[d4+2] + v[3]*ah[d4+3];
  float s2 = v[0]*ah[64+d4] + v[1]*ah[64+d4+1] + v[2]*ah[64+d4+2] + v[3]*ah[64+d4+3];
#pragma unroll
  for (int o = 8; o >= 1; o >>= 1) {
    s1 += __shfl_xor(s1, o);
    s2 += __shfl_xor(s2, o);
  }
  float s2s = s2 * LOG2E;
  if ((lane & 15) == 0) {
    f1L[h * N_NODES + n] = s1 * LOG2E;
    E2p[h * N_NODES + n] = __float2bfloat16(EXP2(s2s));
    E2n[h * N_NODES + n] = __float2bfloat16(EXP2(0.2f * s2s));
    bm[wv][h] = s2s;
  }
  __syncthreads();
  if (t < 4)
    pmax[blockIdx.x * 4 + t] =
        fmaxf(fmaxf(bm[0][t], bm[1][t]), fmaxf(bm[2][t], bm[3][t]));
}

// ---------------- final per-head max over 1024 block partials -------------
__global__ __launch_bounds__(256) void fmax_final_kernel(
    const float* __restrict__ pmax, float* __restrict__ f2max)
{
  __shared__ float red[256];
  int h = blockIdx.x, t = threadIdx.x;
  float m = -1e30f;
  for (int i = t; i < 1024; i += 256) m = fmaxf(m, pmax[i * 4 + h]);
  red[t] = m;
  __syncthreads();
  for (int s = 128; s > 0; s >>= 1) {
    if (t < s) red[t] = fmaxf(red[t], red[t + s]);
    __syncthreads();
  }
  if (t == 0) f2max[h] = red[0];
}

// ---------------- fused masked-softmax-numerator @ h  --------------------
// grid (NC, 32, 4): block covers 128 i-rows. 4 waves; each wave owns 2
// i-groups of 16 rows (i0+wv*16 and i0+64+wv*16) sharing V-fragment loads.
// NO LDS, NO barriers: V fragments (hT is already B-fragment layout) and
// E tables load straight from global; compiler pipelines across tiles.
__global__ __launch_bounds__(256, 4) void attn_kernel(
    const __hip_bfloat16* __restrict__ hThi,   // [256][4096], row c = h*64+d
    const float* __restrict__ f1L,
    const __hip_bfloat16* __restrict__ E2p, const __hip_bfloat16* __restrict__ E2n,
    const float* __restrict__ f2max,
    const unsigned long long* __restrict__ bits64, // [4096][64]
    float* __restrict__ pbuf, float* __restrict__ lbuf, int Jc)
{
  int t = threadIdx.x;
  int wv = t >> 6, lane = t & 63, quad = lane >> 4, col = lane & 15;
  int ch = blockIdx.x, it = blockIdx.y, h = blockIdx.z;
  int i0 = it * 128;
  int irow0 = i0 + wv * 16 + col;
  int irow1 = irow0 + 64;
  int j0c = ch * Jc;
  int T = Jc >> 6;

  float f2m = f2max[h];
  float f1a = f1L[h * N_NODES + irow0];
  float f1b = f1L[h * N_NODES + irow1];
  float sa = f1a + f2m, sb = f1b + f2m;
  float ma = fmaxf(sa, 0.2f * sa);  // lrelu monotone -> valid upper-bound shift
  float mb = fmaxf(sb, 0.2f * sb);
  float Ap0 = EXP2(f1a - ma), An0 = EXP2(__builtin_fmaf(0.2f, f1a, -ma));
  float Ap1 = EXP2(f1b - mb), An1 = EXP2(__builtin_fmaf(0.2f, f1b, -mb));

  const unsigned short* H =
      reinterpret_cast<const unsigned short*>(hThi) + (size_t)h * 64 * N_NODES;
  const unsigned short* Vb = H + (size_t)col * N_NODES + quad * 8; // +db*16 rows
  const unsigned short* EpB =
      reinterpret_cast<const unsigned short*>(E2p) + h * N_NODES + quad * 8;
  const unsigned short* EnB =
      reinterpret_cast<const unsigned short*>(E2n) + h * N_NODES + quad * 8;
  const unsigned long long* br0 = bits64 + (size_t)irow0 * 64;
  const unsigned long long* br1 = bits64 + (size_t)irow1 * 64;

  float4v acc[2][4] = {{{0,0,0,0},{0,0,0,0},{0,0,0,0},{0,0,0,0}},
                       {{0,0,0,0},{0,0,0,0},{0,0,0,0},{0,0,0,0}}};
  float4v accl[2] = {{0,0,0,0},{0,0,0,0}};
  S8U ones;
  ones.u[0] = ones.u[1] = ones.u[2] = ones.u[3] = 0x3F803F80u; // bf16 1.0 x2

  for (int ti = 0; ti < T; ++ti) {
    int j0 = j0c + ti * 64;
    S8U ep[2], en[2];
    ep[0].v = *reinterpret_cast<const short8*>(EpB + j0);
    ep[1].v = *reinterpret_cast<const short8*>(EpB + j0 + 32);
    en[0].v = *reinterpret_cast<const short8*>(EnB + j0);
    en[1].v = *reinterpret_cast<const short8*>(EnB + j0 + 32);
    unsigned long long q0 = br0[j0 >> 6] >> (quad * 8);
    unsigned long long q1 = br1[j0 >> 6] >> (quad * 8);

    S8U afr[2][2];  // [ig][jh]
#pragma unroll
    for (int jh = 0; jh < 2; ++jh) {
      unsigned int m0 = (unsigned int)(q0 >> (jh * 32));
      unsigned int m1 = (unsigned int)(q1 >> (jh * 32));
#pragma unroll
      for (int k2 = 0; k2 < 4; ++k2) {
        unsigned int up = ep[jh].u[k2], un = en[jh].u[k2];
        float p0 = __uint_as_float(up << 16);
        float p1 = __uint_as_float(up & 0xFFFF0000u);
        float n0 = __uint_as_float(un << 16);
        float n1 = __uint_as_float(un & 0xFFFF0000u);
        float e00 = fmaxf(Ap0 * p0, An0 * n0);
        float e01 = fmaxf(Ap0 * p1, An0 * n1);
        float e10 = fmaxf(Ap1 * p0, An1 * n0);
        float e11 = fmaxf(Ap1 * p1, An1 * n1);
        float w00 = (m0 & (1u << (2 * k2)))     ? e00 : 0.0f;
        float w01 = (m0 & (1u << (2 * k2 + 1))) ? e01 : 0.0f;
        float w10 = (m1 & (1u << (2 * k2)))     ? e10 : 0.0f;
        float w11 = (m1 & (1u << (2 * k2 + 1))) ? e11 : 0.0f;
        afr[0][jh].u[k2] = __builtin_amdgcn_perm(__float_as_uint(w01),
                                                 __float_as_uint(w00), 0x07060302u);
        afr[1][jh].u[k2] = __builtin_amdgcn_perm(__float_as_uint(w11),
                                                 __float_as_uint(w10), 0x07060302u);
      }
    }
#pragma unroll
    for (int db = 0; db < 4; ++db) {
      const unsigned short* vp = Vb + (size_t)(db * 16) * N_NODES + j0;
      short8 b0 = *reinterpret_cast<const short8*>(vp);
      short8 b1 = *reinterpret_cast<const short8*>(vp + 32);
      acc[0][db] = __builtin_amdgcn_mfma_f32_16x16x32_bf16(afr[0][0].v, b0, acc[0][db], 0, 0, 0);
      acc[1][db] = __builtin_amdgcn_mfma_f32_16x16x32_bf16(afr[1][0].v, b0, acc[1][db], 0, 0, 0);
      acc[0][db] = __builtin_amdgcn_mfma_f32_16x16x32_bf16(afr[0][1].v, b1, acc[0][db], 0, 0, 0);
      acc[1][db] = __builtin_amdgcn_mfma_f32_16x16x32_bf16(afr[1][1].v, b1, acc[1][db], 0, 0, 0);
    }
    accl[0] = __builtin_amdgcn_mfma_f32_16x16x32_bf16(afr[0][0].v, ones.v, accl[0], 0, 0, 0);
    accl[0] = __builtin_amdgcn_mfma_f32_16x16x32_bf16(afr[0][1].v, ones.v, accl[0], 0, 0, 0);
    accl[1] = __builtin_amdgcn_mfma_f32_16x16x32_bf16(afr[1][0].v, ones.v, accl[1], 0, 0, 0);
    accl[1] = __builtin_amdgcn_mfma_f32_16x16x32_bf16(afr[1][1].v, ones.v, accl[1], 0, 0, 0);
  }

  // C/D layout: col=lane&15, row=quad*4+reg
#pragma unroll
  for (int ig = 0; ig < 2; ++ig) {
    float* pb = pbuf + ((size_t)(ch * 4 + h) * N_NODES + i0 + ig * 64 + wv * 16) * 64;
#pragma unroll
    for (int db = 0; db < 4; ++db)
#pragma unroll
      for (int r = 0; r < 4; ++r)
        pb[(quad * 4 + r) * 64 + db * 16 + col] = acc[ig][db][r];
    if (col == 0) {
      float* lb = lbuf + (size_t)(ch * 4 + h) * N_NODES + i0 + ig * 64 + wv * 16;
#pragma unroll
      for (int r = 0; r < 4; ++r) lb[quad * 4 + r] = accl[ig][r];
    }
  }
}

// ------- combine chunks, normalize, elu; fp32 OR split-bf16 (x4 vec) -----
// grid 1024, block 256: thread handles 4 consecutive d of one (n,h).
__global__ __launch_bounds__(256) void reduce_elu_kernel(
    const float* __restrict__ pbuf, const float* __restrict__ lbuf,
    float* __restrict__ outf, __hip_bfloat16* __restrict__ outhi,
    __hip_bfloat16* __restrict__ outlo, int NC)
{
  int idx = blockIdx.x * 256 + threadIdx.x;   // 262144 total
  int n = idx >> 6, c4 = (idx & 63) * 4;
  int h = c4 >> 6, d = c4 & 63;
  float4v s = {0, 0, 0, 0};
  float l = 0.f;
  for (int ch = 0; ch < NC; ++ch) {
    size_t b = ((size_t)(ch * 4 + h) * N_NODES + n);
    float4v pv = *reinterpret_cast<const float4v*>(pbuf + b * 64 + d);
    s += pv;
    l += lbuf[b];
  }
  float rl = 1.0f / l;
  float o[4];
#pragma unroll
  for (int r = 0; r < 4; ++r) {
    float v = s[r] * rl;
    o[r] = v > 0.f ? v : EXP2(v * LOG2E) - 1.0f;
  }
  size_t oo = (size_t)n * DIMC + c4;
  if (outf) {
    *reinterpret_cast<float4v*>(outf + oo) = {o[0], o[1], o[2], o[3]};
  } else {
    short4v oh, ol;
#pragma unroll
    for (int r = 0; r < 4; ++r) {
      __hip_bfloat16 hb = __float2bfloat16(o[r]);
      oh[r] = (short)bf16_bits(hb);
      ol[r] = (short)bf16_bits(__float2bfloat16(o[r] - __bfloat162float(hb)));
    }
    *reinterpret_cast<short4v*>(reinterpret_cast<unsigned short*>(outhi) + oo) = oh;
    *reinterpret_cast<short4v*>(reinterpret_cast<unsigned short*>(outlo) + oo) = ol;
  }
}

extern "C" void kernel_launch(void* const* d_in, const int* in_sizes, int n_in,
                              void* d_out, int out_size, void* d_ws, size_t ws_size,
                              hipStream_t stream)
{
  // inputs: t, x, adj, W1, a1, W2, a2  (fp32 except adj int32)
  const float* x   = (const float*)d_in[1];
  const int*   adj = (const int*)d_in[2];
  const float* W1  = (const float*)d_in[3];
  const float* a1  = (const float*)d_in[4];
  const float* W2  = (const float*)d_in[5];
  const float* a2  = (const float*)d_in[6];

  char* ws = (char*)d_ws;
  size_t off = 0;
  auto alloc = [&](size_t b) { size_t o = off; off = (off + b + 255) & ~255ULL; return o; };
  size_t o_bits = alloc((size_t)N_NODES * 64 * 8);          // 2 MB bitmask
  size_t o_w1h  = alloc((size_t)DIMC * DIMC * 2);
  size_t o_w1l  = alloc((size_t)DIMC * DIMC * 2);
  size_t o_w2h  = alloc((size_t)DIMC * DIMC * 2);
  size_t o_w2l  = alloc((size_t)DIMC * DIMC * 2);
  size_t o_xh   = alloc((size_t)N_NODES * DIMC * 2);
  size_t o_xl   = alloc((size_t)N_NODES * DIMC * 2);
  size_t o_hA   = alloc((size_t)N_NODES * DIMC * 4);        // h fp32 row-major
  size_t o_hTh  = alloc((size_t)N_NODES * DIMC * 2);        // h^T bf16 (from gemm)
  size_t o_x2h  = alloc((size_t)N_NODES * DIMC * 2);
  size_t o_x2l  = alloc((size_t)N_NODES * DIMC * 2);
  size_t o_f1   = alloc((size_t)NHEADS * N_NODES * 4);
  size_t o_ep   = alloc((size_t)NHEADS * N_NODES * 2);      // bf16 exp tables
  size_t o_en   = alloc((size_t)NHEADS * N_NODES * 2);
  size_t o_pm   = alloc((size_t)1024 * 4 * 4);              // per-block head maxes
  size_t o_fm   = alloc(256);                               // 2 layers x 4 floats

  size_t per_chunk = (size_t)NHEADS * N_NODES * 64 * 4 + (size_t)NHEADS * N_NODES * 4 + 512;
  int NC = 8;
  while (NC > 1 && off + (size_t)NC * per_chunk > ws_size) NC >>= 1;
  size_t o_pb = alloc((size_t)NC * NHEADS * N_NODES * 64 * 4);
  size_t o_lb = alloc((size_t)NC * NHEADS * N_NODES * 4);

  unsigned long long* bits = (unsigned long long*)(ws + o_bits);
  __hip_bfloat16* w1h = (__hip_bfloat16*)(ws + o_w1h);
  __hip_bfloat16* w1l = (__hip_bfloat16*)(ws + o_w1l);
  __hip_bfloat16* w2h = (__hip_bfloat16*)(ws + o_w2h);
  __hip_bfloat16* w2l = (__hip_bfloat16*)(ws + o_w2l);
  __hip_bfloat16* xh  = (__hip_bfloat16*)(ws + o_xh);
  __hip_bfloat16* xl  = (__hip_bfloat16*)(ws + o_xl);
  float*          hA  = (float*)(ws + o_hA);
  __hip_bfloat16* hTh = (__hip_bfloat16*)(ws + o_hTh);
  __hip_bfloat16* x2h = (__hip_bfloat16*)(ws + o_x2h);
  __hip_bfloat16* x2l = (__hip_bfloat16*)(ws + o_x2l);
  float* f1p = (float*)(ws + o_f1);
  __hip_bfloat16* epp = (__hip_bfloat16*)(ws + o_ep);
  __hip_bfloat16* enp = (__hip_bfloat16*)(ws + o_en);
  float* pmx = (float*)(ws + o_pm);
  float* fmp = (float*)(ws + o_fm);
  float* pb  = (float*)(ws + o_pb);
  float* lb  = (float*)(ws + o_lb);

  pack_adj_kernel<<<N_NODES * 64 / 4, 256, 0, stream>>>(adj, bits);
  transpose_split_kernel<<<dim3(8, 2, 4), 256, 0, stream>>>(W1, w1h, w1l, 256, 64);
  transpose_split_kernel<<<dim3(8, 2, 4), 256, 0, stream>>>(W2, w2h, w2l, 256, 64);
  split_kernel<<<N_NODES * DIMC / 256, 256, 0, stream>>>(x, xh, xl, N_NODES * DIMC);

  auto layer = [&](const __hip_bfloat16* xih, const __hip_bfloat16* xil,
                   const __hip_bfloat16* wth, const __hip_bfloat16* wtl,
                   const float* av, float* fmk, float* outf,
                   __hip_bfloat16* oh, __hip_bfloat16* ol) {
    gemm_kernel<<<dim3(128, 8), 256, 0, stream>>>(xih, xil, wth, wtl, hA, hTh);
    fvec_kernel<<<1024, 256, 0, stream>>>(hA, av, f1p, epp, enp, pmx);
    fmax_final_kernel<<<4, 256, 0, stream>>>(pmx, fmk);
    attn_kernel<<<dim3(NC, N_NODES / 128, 4), 256, 0, stream>>>(
        hTh, f1p, epp, enp, fmk, bits, pb, lb, N_NODES / NC);
    reduce_elu_kernel<<<1024, 256, 0, stream>>>(pb, lb, outf, oh, ol, NC);
  };

  layer(xh,  xl,  w1h, w1l, a1, fmp,     nullptr,        x2h, x2l);
  layer(x2h, x2l, w2h, w2l, a2, fmp + 4, (float*)d_out,  nullptr, nullptr);
}